// Round 2
// baseline (1751.683 us; speedup 1.0000x reference)
//
#include <hip/hip_runtime.h>
#include <hip/hip_fp16.h>
#include <math.h>

#define HID  128
#define EDIM 416
#define CATD 672      // 2*HID + EDIM
#define NN   10000
#define NE   160000
#define EB   128      // edges per block (edge kernel)
#define NT   64       // nodes per block (node kernel)
#define KT   32       // K tile (node kernel)

typedef _Float16 f16x8 __attribute__((ext_vector_type(8)));
typedef float    f32x4 __attribute__((ext_vector_type(4)));

__device__ __forceinline__ float silu_f(float x) {
    return x / (1.0f + __expf(-x));
}

__device__ __forceinline__ unsigned int cvt2(float a, float b) {
    __half2 h = __floats2half2_rn(a, b);
    union { __half2 h2; unsigned int u; } c; c.h2 = h; return c.u;
}

// pack 8 fp32 (as raw bits in 2 uint4) -> 8 f16 in one uint4
__device__ __forceinline__ uint4 pack8(uint4 a, uint4 b) {
    uint4 p;
    p.x = cvt2(__uint_as_float(a.x), __uint_as_float(a.y));
    p.y = cvt2(__uint_as_float(a.z), __uint_as_float(a.w));
    p.z = cvt2(__uint_as_float(b.x), __uint_as_float(b.y));
    p.w = cvt2(__uint_as_float(b.z), __uint_as_float(b.w));
    return p;
}

// 16-B-granule XOR swizzle helpers.
// Tiles with 64-B rows (32 halves): granule ks in [0,4), swizzled by row bits.
__device__ __forceinline__ f16x8 frag32(const __half* base, int row, int ks) {
    return *reinterpret_cast<const f16x8*>(base + row * 32 + ((ks ^ ((row >> 1) & 3)) << 3));
}
// Tiles with 256-B rows (128 halves): granule g in [0,16).
__device__ __forceinline__ int swz128(int row, int g) { return (g & 8) | ((g ^ row) & 7); }
__device__ __forceinline__ f16x8 frag128(const __half* base, int row, int g) {
    return *reinterpret_cast<const f16x8*>(base + row * 128 + (swz128(row, g) << 3));
}

// ---------------- LayerNorm: one wave per node; emits fp32 + fp16 ----------------
__global__ __launch_bounds__(256) void ln_kernel(const float* __restrict__ x,
                                                 const float* __restrict__ g,
                                                 const float* __restrict__ b,
                                                 float* __restrict__ xh,
                                                 __half* __restrict__ xh_h) {
    int node = blockIdx.x * 4 + (threadIdx.x >> 6);
    int lane = threadIdx.x & 63;
    if (node >= NN) return;
    const float* xr = x + (size_t)node * HID;
    float v0 = xr[lane], v1 = xr[lane + 64];
    float s = v0 + v1;
    #pragma unroll
    for (int off = 1; off < 64; off <<= 1) s += __shfl_xor(s, off);
    float mu = s * (1.0f / HID);
    float d0 = v0 - mu, d1 = v1 - mu;
    float vs = d0 * d0 + d1 * d1;
    #pragma unroll
    for (int off = 1; off < 64; off <<= 1) vs += __shfl_xor(vs, off);
    float rstd = rsqrtf(vs * (1.0f / HID) + 1e-5f);
    float r0 = d0 * rstd * g[lane]      + b[lane];
    float r1 = d1 * rstd * g[lane + 64] + b[lane + 64];
    float* o = xh + (size_t)node * HID;
    o[lane] = r0; o[lane + 64] = r1;
    __half* oh = xh_h + (size_t)node * HID;
    oh[lane]      = __float2half(r0);
    oh[lane + 64] = __float2half(r1);
}

// ---------------- Weight pack: fp32 -> fp16, B-fragment order, swizzle baked in ---
__global__ __launch_bounds__(256) void pack_kernel(
    const float* __restrict__ We1, const float* __restrict__ We2,
    const float* __restrict__ Wo,
    __half* __restrict__ We1p, __half* __restrict__ We2p, __half* __restrict__ Wop)
{
    int gid = blockIdx.x * 256 + threadIdx.x;
    if (gid < 10752) {                       // We1p: 21 tiles x 512 granules
        int kt = gid >> 9, r = gid & 511, col = r >> 2, kx = r & 3;
        __half* d = We1p + kt * 4096 + col * 32 + ((kx ^ ((col >> 1) & 3)) << 3);
        int k0 = kt * 32 + kx * 8;
        #pragma unroll
        for (int u = 0; u < 8; ++u) d[u] = __float2half(We1[(size_t)(k0 + u) * HID + col]);
    } else if (gid < 12800) {                // We2p: 4 tiles x 512
        int r2 = gid - 10752;
        int kt = r2 >> 9, r = r2 & 511, col = r >> 2, kx = r & 3;
        __half* d = We2p + kt * 4096 + col * 32 + ((kx ^ ((col >> 1) & 3)) << 3);
        int k0 = kt * 32 + kx * 8;
        #pragma unroll
        for (int u = 0; u < 8; ++u) d[u] = __float2half(We2[(size_t)(k0 + u) * HID + col]);
    } else if (gid < 18944) {                // Wop chunks 0..2: 3 x 4 tiles x 512
        int r3 = gid - 12800;
        int nc = r3 >> 11, r2 = r3 & 2047;
        int kt = r2 >> 9, r = r2 & 511, col = r >> 2, kx = r & 3;
        __half* d = Wop + nc * 16384 + kt * 4096 + col * 32 + ((kx ^ ((col >> 1) & 3)) << 3);
        int k0 = kt * 32 + kx * 8, cg = nc * 128 + col;
        #pragma unroll
        for (int u = 0; u < 8; ++u) d[u] = __float2half(Wo[(size_t)(k0 + u) * EDIM + cg]);
    } else if (gid < 19456) {                // Wop chunk 3 (cols 384..415): 4 tiles x 128
        int r3 = gid - 18944;
        int kt = r3 >> 7, r = r3 & 127, col = r >> 2, kx = r & 3;
        __half* d = Wop + 49152 + kt * 1024 + col * 32 + ((kx ^ ((col >> 1) & 3)) << 3);
        int k0 = kt * 32 + kx * 8, cg = 384 + col;
        #pragma unroll
        for (int u = 0; u < 8; ++u) d[u] = __float2half(Wo[(size_t)(k0 + u) * EDIM + cg]);
    }
}

// ---------------- Edge kernel: 128 edges/block, 4 waves (2x2), f16 MFMA ----------
// Double-buffered K-loops (1 barrier/iter), atomics deferred to kernel end.
__global__ __launch_bounds__(256, 3) void edge_kernel(
    const __half* __restrict__ xh_h,
    const float*  __restrict__ weight,
    const __half* __restrict__ We1p, const float* __restrict__ be1,
    const __half* __restrict__ We2p, const float* __restrict__ be2,
    const float*  __restrict__ Wa,   const float* __restrict__ ba,
    const __half* __restrict__ Wop,  const float* __restrict__ bo,
    const int* __restrict__ ii, const int* __restrict__ jj,
    float* __restrict__ agg, float* __restrict__ cnt,
    float* __restrict__ edgeh)
{
    __shared__ __half smem[24576];        // 48 KB: A0(4096h) B0(4096h) ml(16384h)
    __shared__ float  attv[EB];
    __shared__ float  Was[HID];
    __shared__ int    iis_s[EB], jjs_s[EB];

    __half* const A0 = smem;
    __half* const B0 = smem + 4096;
    __half* const ml = smem + 8192;
    __half* const A1 = ml;                // alias: GEMM1 only (ml not yet live)
    __half* const B1 = ml + 4096;         // alias: GEMM1 only

    const int t    = threadIdx.x;
    const int e0   = blockIdx.x * EB;
    const int lane = t & 63;
    const int w    = t >> 6;
    const int wr   = w >> 1, wc = w & 1;  // wave owns rows [wr*64,+64) x cols [wc*64,+64)
    const int li   = lane & 15, ks = lane >> 4;
    const int rbw  = wr * 64, cbw = wc * 64;
    const int e_lo = t >> 2, kx = t & 3;  // A-staging: rows e_lo, e_lo+64, granule kx
    const int sw_lo = ((kx ^ ((e_lo >> 1) & 3)) << 3);   // same for row e_lo+64

    if (t < EB) { iis_s[t] = ii[e0 + t]; jjs_s[t] = jj[e0 + t]; }
    if (t < HID) Was[t] = Wa[t];
    __syncthreads();

    // ---- GEMM1 prologue: stage tile 0 (xh[ii] k 0..31 + We1 tile 0) ----
    {
        int n0 = iis_s[e_lo], n1 = iis_s[e_lo + 64];
        uint4 a0v = *(const uint4*)(xh_h + (size_t)n0 * HID + kx * 8);
        uint4 a1v = *(const uint4*)(xh_h + (size_t)n1 * HID + kx * 8);
        uint4 b0v = *(const uint4*)(We1p + t * 8);
        uint4 b1v = *(const uint4*)(We1p + 2048 + t * 8);
        *(uint4*)(A0 + e_lo * 32 + sw_lo) = a0v;
        *(uint4*)(A0 + (e_lo + 64) * 32 + sw_lo) = a1v;
        *(uint4*)(B0 + t * 8) = b0v;
        *(uint4*)(B0 + 2048 + t * 8) = b1v;
    }
    __syncthreads();

    // ================= GEMM1: cat(672) @ We1 -> 128 (double-buffered) =========
    f32x4 acc[4][4];
    #pragma unroll
    for (int fr = 0; fr < 4; ++fr)
        #pragma unroll
        for (int fc = 0; fc < 4; ++fc) {
            acc[fr][fc][0] = 0.f; acc[fr][fc][1] = 0.f;
            acc[fr][fc][2] = 0.f; acc[fr][fc][3] = 0.f;
        }

    #pragma unroll 1
    for (int kt = 0; kt < 21; ++kt) {
        const int ktn = kt + 1;
        uint4 pa0, pa1, pa2, pa3, pb0, pb1;
        if (ktn < 21) {
            const __half* bsrc = We1p + ktn * 4096;
            pb0 = *(const uint4*)(bsrc + t * 8);
            pb1 = *(const uint4*)(bsrc + 2048 + t * 8);
            if (ktn < 8) {
                int n0 = (ktn < 4) ? iis_s[e_lo] : jjs_s[e_lo];
                int n1 = (ktn < 4) ? iis_s[e_lo + 64] : jjs_s[e_lo + 64];
                pa0 = *(const uint4*)(xh_h + (size_t)n0 * HID + (ktn & 3) * 32 + kx * 8);
                pa1 = *(const uint4*)(xh_h + (size_t)n1 * HID + (ktn & 3) * 32 + kx * 8);
            } else {
                const float* s0p = weight + (size_t)(e0 + e_lo) * EDIM + (ktn - 8) * 32 + kx * 8;
                const float* s1p = weight + (size_t)(e0 + e_lo + 64) * EDIM + (ktn - 8) * 32 + kx * 8;
                pa0 = ((const uint4*)s0p)[0]; pa1 = ((const uint4*)s0p)[1];
                pa2 = ((const uint4*)s1p)[0]; pa3 = ((const uint4*)s1p)[1];
            }
        }
        // MFMA on current buffer
        const __half* Ac = (kt & 1) ? A1 : A0;
        const __half* Bc = (kt & 1) ? B1 : B0;
        f16x8 av[4], bv[4];
        #pragma unroll
        for (int fr = 0; fr < 4; ++fr) av[fr] = frag32(Ac, rbw + fr * 16 + li, ks);
        #pragma unroll
        for (int fc = 0; fc < 4; ++fc) bv[fc] = frag32(Bc, cbw + fc * 16 + li, ks);
        #pragma unroll
        for (int fr = 0; fr < 4; ++fr)
            #pragma unroll
            for (int fc = 0; fc < 4; ++fc)
                acc[fr][fc] = __builtin_amdgcn_mfma_f32_16x16x32_f16(av[fr], bv[fc], acc[fr][fc], 0, 0, 0);
        // write next tile to the other buffer
        if (ktn < 21) {
            __half* An = (ktn & 1) ? A1 : A0;
            __half* Bn = (ktn & 1) ? B1 : B0;
            *(uint4*)(Bn + t * 8) = pb0;
            *(uint4*)(Bn + 2048 + t * 8) = pb1;
            if (ktn < 8) {
                *(uint4*)(An + e_lo * 32 + sw_lo) = pa0;
                *(uint4*)(An + (e_lo + 64) * 32 + sw_lo) = pa1;
            } else {
                *(uint4*)(An + e_lo * 32 + sw_lo) = pack8(pa0, pa1);
                *(uint4*)(An + (e_lo + 64) * 32 + sw_lo) = pack8(pa2, pa3);
            }
        }
        __syncthreads();
    }

    // m1 = silu(acc + be1) -> ml (safe: final loop barrier drained all reads)
    #pragma unroll
    for (int fc = 0; fc < 4; ++fc) {
        int c = cbw + fc * 16 + li;
        float bias = be1[c];
        int gc = c >> 3;
        #pragma unroll
        for (int fr = 0; fr < 4; ++fr)
            #pragma unroll
            for (int bb = 0; bb < 4; ++bb) {
                int e = rbw + fr * 16 + 4 * ks + bb;   // D row = 4*(lane>>4)+reg
                ml[e * 128 + (swz128(e, gc) << 3) + (c & 7)] =
                    __float2half(silu_f(acc[fr][fc][bb] + bias));
            }
    }
    // GEMM2 prologue: stage We2 tile 0 into B0 (disjoint from ml)
    {
        uint4 b0v = *(const uint4*)(We2p + t * 8);
        uint4 b1v = *(const uint4*)(We2p + 2048 + t * 8);
        *(uint4*)(B0 + t * 8) = b0v;
        *(uint4*)(B0 + 2048 + t * 8) = b1v;
    }
    __syncthreads();

    // ================= GEMM2: m1(128) @ We2 -> 128 (B double-buffered B0/A0) ====
    f32x4 acc2[4][4];
    #pragma unroll
    for (int fr = 0; fr < 4; ++fr)
        #pragma unroll
        for (int fc = 0; fc < 4; ++fc) {
            acc2[fr][fc][0] = 0.f; acc2[fr][fc][1] = 0.f;
            acc2[fr][fc][2] = 0.f; acc2[fr][fc][3] = 0.f;
        }
    #pragma unroll 1
    for (int kt = 0; kt < 4; ++kt) {
        uint4 pb0, pb1;
        if (kt < 3) {
            const __half* bsrc = We2p + (kt + 1) * 4096;
            pb0 = *(const uint4*)(bsrc + t * 8);
            pb1 = *(const uint4*)(bsrc + 2048 + t * 8);
        }
        const __half* Bc = (kt & 1) ? A0 : B0;
        f16x8 av[4], bv[4];
        #pragma unroll
        for (int fr = 0; fr < 4; ++fr) av[fr] = frag128(ml, rbw + fr * 16 + li, kt * 4 + ks);
        #pragma unroll
        for (int fc = 0; fc < 4; ++fc) bv[fc] = frag32(Bc, cbw + fc * 16 + li, ks);
        #pragma unroll
        for (int fr = 0; fr < 4; ++fr)
            #pragma unroll
            for (int fc = 0; fc < 4; ++fc)
                acc2[fr][fc] = __builtin_amdgcn_mfma_f32_16x16x32_f16(av[fr], bv[fc], acc2[fr][fc], 0, 0, 0);
        if (kt < 3) {
            __half* Bn = ((kt + 1) & 1) ? A0 : B0;
            *(uint4*)(Bn + t * 8) = pb0;
            *(uint4*)(Bn + 2048 + t * 8) = pb1;
        }
        __syncthreads();
    }
    // m = silu(acc2 + be2) -> ml (reads of m1 all drained by final loop barrier)
    #pragma unroll
    for (int fc = 0; fc < 4; ++fc) {
        int c = cbw + fc * 16 + li;
        float bias = be2[c];
        int gc = c >> 3;
        #pragma unroll
        for (int fr = 0; fr < 4; ++fr)
            #pragma unroll
            for (int bb = 0; bb < 4; ++bb) {
                int e = rbw + fr * 16 + 4 * ks + bb;
                ml[e * 128 + (swz128(e, gc) << 3) + (c & 7)] =
                    __float2half(silu_f(acc2[fr][fc][bb] + bias));
            }
    }
    __syncthreads();

    // ================= attention: att = silu(m . Wa + ba) =================
    {
        int e = t >> 1, h = t & 1;
        float sum = 0.f;
        #pragma unroll
        for (int g8 = 0; g8 < 8; ++g8) {
            int g = h * 8 + g8;
            uint4 v = *(const uint4*)(ml + e * 128 + (swz128(e, g) << 3));
            const __half* hp = (const __half*)&v;
            #pragma unroll
            for (int u = 0; u < 8; ++u) sum += __half2float(hp[u]) * Was[g * 8 + u];
        }
        sum += __shfl_xor(sum, 1);
        if (h == 0) attv[e] = silu_f(sum + ba[0]);
    }
    __syncthreads();

    // ====== m_ij = m * att (in place, no atomics here) + GEMM3 prologue ======
    {
        int e = t >> 1, h = t & 1;
        __half2 a2 = __float2half2_rn(attv[e]);
        #pragma unroll
        for (int g8 = 0; g8 < 8; ++g8) {
            int g = h * 8 + g8;
            uint4* p4 = (uint4*)(ml + e * 128 + (swz128(e, g) << 3));
            uint4 v = *p4;
            __half2* h2 = (__half2*)&v;
            #pragma unroll
            for (int i = 0; i < 4; ++i) h2[i] = __hmul2(h2[i], a2);
            *p4 = v;
        }
    }
    {   // stage Wop tile L=0 into B0
        uint4 b0v = *(const uint4*)(Wop + t * 8);
        uint4 b1v = *(const uint4*)(Wop + 2048 + t * 8);
        *(uint4*)(B0 + t * 8) = b0v;
        *(uint4*)(B0 + 2048 + t * 8) = b1v;
    }
    __syncthreads();

    // ===== GEMM3: m_ij(128) @ Wo -> 416 (linear 16-tile loop, B dbuf B0/A0) =====
    f32x4 acc3[4][4];
    #pragma unroll 1
    for (int L = 0; L < 16; ++L) {
        const int nc = L >> 2, kt = L & 3;
        if (kt == 0) {
            #pragma unroll
            for (int fr = 0; fr < 4; ++fr)
                #pragma unroll
                for (int fc = 0; fc < 4; ++fc) {
                    acc3[fr][fc][0] = 0.f; acc3[fr][fc][1] = 0.f;
                    acc3[fr][fc][2] = 0.f; acc3[fr][fc][3] = 0.f;
                }
        }
        uint4 pb0, pb1;
        const int Ln = L + 1;
        if (Ln < 16) {
            const int ncn = Ln >> 2, ktn = Ln & 3;
            if (ncn < 3) {
                const __half* bsrc = Wop + ncn * 16384 + ktn * 4096;
                pb0 = *(const uint4*)(bsrc + t * 8);
                pb1 = *(const uint4*)(bsrc + 2048 + t * 8);
            } else if (t < 128) {
                pb0 = *(const uint4*)(Wop + 49152 + ktn * 1024 + t * 8);
            }
        }
        const __half* Bc = (L & 1) ? A0 : B0;
        f16x8 av[4];
        #pragma unroll
        for (int fr = 0; fr < 4; ++fr) av[fr] = frag128(ml, rbw + fr * 16 + li, kt * 4 + ks);
        if (nc < 3) {
            f16x8 bv[4];
            #pragma unroll
            for (int fc = 0; fc < 4; ++fc) bv[fc] = frag32(Bc, cbw + fc * 16 + li, ks);
            #pragma unroll
            for (int fr = 0; fr < 4; ++fr)
                #pragma unroll
                for (int fc = 0; fc < 4; ++fc)
                    acc3[fr][fc] = __builtin_amdgcn_mfma_f32_16x16x32_f16(av[fr], bv[fc], acc3[fr][fc], 0, 0, 0);
        } else {
            f16x8 bv = frag32(Bc, wc * 16 + li, ks);
            #pragma unroll
            for (int fr = 0; fr < 4; ++fr)
                acc3[fr][0] = __builtin_amdgcn_mfma_f32_16x16x32_f16(av[fr], bv, acc3[fr][0], 0, 0, 0);
        }
        if (Ln < 16) {
            __half* Bn = (Ln & 1) ? A0 : B0;
            if ((Ln >> 2) < 3) {
                *(uint4*)(Bn + t * 8) = pb0;
                *(uint4*)(Bn + 2048 + t * 8) = pb1;
            } else if (t < 128) {
                *(uint4*)(Bn + t * 8) = pb0;
            }
        }
        __syncthreads();
        if (kt == 3) {
            if (nc < 3) {
                #pragma unroll
                for (int fc = 0; fc < 4; ++fc) {
                    int cg = nc * 128 + cbw + fc * 16 + li;
                    float bias = bo[cg];
                    #pragma unroll
                    for (int fr = 0; fr < 4; ++fr)
                        #pragma unroll
                        for (int bb = 0; bb < 4; ++bb) {
                            int e = rbw + fr * 16 + 4 * ks + bb;
                            size_t idx = (size_t)(e0 + e) * EDIM + cg;
                            edgeh[idx] = weight[idx] + silu_f(acc3[fr][fc][bb] + bias);
                        }
                }
            } else {
                int cg = 384 + wc * 16 + li;
                float bias = bo[cg];
                #pragma unroll
                for (int fr = 0; fr < 4; ++fr)
                    #pragma unroll
                    for (int bb = 0; bb < 4; ++bb) {
                        int e = rbw + fr * 16 + 4 * ks + bb;
                        size_t idx = (size_t)(e0 + e) * EDIM + cg;
                        edgeh[idx] = weight[idx] + silu_f(acc3[fr][0][bb] + bias);
                    }
            }
        }
    }

    // ====== deferred mean-agg atomics: fire at kernel end, drain at endpgm ======
    {
        int e = t >> 1, h = t & 1;
        int node = iis_s[e];
        float* aggrow = agg + (size_t)node * HID;
        #pragma unroll
        for (int g8 = 0; g8 < 8; ++g8) {
            int g = h * 8 + g8;
            uint4 v = *(const uint4*)(ml + e * 128 + (swz128(e, g) << 3));
            const __half* hp = (const __half*)&v;
            #pragma unroll
            for (int u = 0; u < 8; ++u)
                atomicAdd(aggrow + g * 8 + u, __half2float(hp[u]));
        }
        if (h == 0) atomicAdd(&cnt[node], 1.0f);
    }
}

// ---------------- Node kernel: 64 nodes x 128 outs per block (fp32) ----------
__global__ __launch_bounds__(256) void node_kernel(
    const float* __restrict__ xh,
    const float* __restrict__ agg, const float* __restrict__ cnt,
    const float* __restrict__ Wn1, const float* __restrict__ bn1,
    const float* __restrict__ Wn2, const float* __restrict__ bn2,
    float* __restrict__ out)
{
    __shared__ float catile[NT][KT + 1];
    __shared__ float wls[KT][HID];
    __shared__ float mls[NT][HID + 4];
    __shared__ float inv[NT];

    int t   = threadIdx.x;
    int n0b = blockIdx.x * NT;

    if (t < NT) {
        int n = n0b + t;
        float c = (n < NN) ? cnt[n] : 1.f;
        inv[t] = (c == 0.f) ? 1.f : 1.f / c;
    }

    int ec = t & 15, og = t >> 4, o0 = og * 8;

    float acc[4][8];
    #pragma unroll
    for (int r = 0; r < 4; ++r)
        #pragma unroll
        for (int c = 0; c < 8; ++c) acc[r][c] = 0.f;

    for (int kt = 0; kt < (2 * HID) / KT; ++kt) {
        int k0 = kt * KT;
        __syncthreads();
        #pragma unroll
        for (int j = 0; j < 8; ++j) {
            int idx = t + j * 256;
            int e = idx >> 5, k = idx & 31;
            int kk = k0 + k;
            int n = n0b + e;
            float v = 0.f;
            if (n < NN) {
                if (kk < HID) v = xh[(size_t)n * HID + kk];
                else          v = agg[(size_t)n * HID + (kk - HID)] * inv[e];
            }
            catile[e][k] = v;
        }
        #pragma unroll
        for (int j = 0; j < 16; ++j) {
            int idx = t + j * 256;
            int k = idx >> 7, o = idx & 127;
            wls[k][o] = Wn1[(size_t)(k0 + k) * HID + o];
        }
        __syncthreads();
        #pragma unroll
        for (int k = 0; k < KT; ++k) {
            float a[4], ww[8];
            #pragma unroll
            for (int r = 0; r < 4; ++r) a[r] = catile[ec + 16 * r][k];
            #pragma unroll
            for (int c = 0; c < 8; ++c) ww[c] = wls[k][o0 + c];
            #pragma unroll
            for (int r = 0; r < 4; ++r)
                #pragma unroll
                for (int c = 0; c < 8; ++c) acc[r][c] += a[r] * ww[c];
        }
    }
    {
        float bias[8];
        #pragma unroll
        for (int c = 0; c < 8; ++c) bias[c] = bn1[o0 + c];
        #pragma unroll
        for (int r = 0; r < 4; ++r)
            #pragma unroll
            for (int c = 0; c < 8; ++c)
                mls[ec + 16 * r][o0 + c] = silu_f(acc[r][c] + bias[c]);
    }

    float acc2[4][8];
    #pragma unroll
    for (int r = 0; r < 4; ++r)
        #pragma unroll
        for (int c = 0; c < 8; ++c) acc2[r][c] = 0.f;

    for (int kt = 0; kt < HID / KT; ++kt) {
        __syncthreads();
        #pragma unroll
        for (int j = 0; j < 16; ++j) {
            int idx = t + j * 256;
            int k = idx >> 7, o = idx & 127;
            wls[k][o] = Wn2[(size_t)(kt * KT + k) * HID + o];
        }
        __syncthreads();
        #pragma unroll
        for (int k = 0; k < KT; ++k) {
            float a[4], ww[8];
            #pragma unroll
            for (int r = 0; r < 4; ++r) a[r] = mls[ec + 16 * r][kt * KT + k];
            #pragma unroll
            for (int c = 0; c < 8; ++c) ww[c] = wls[k][o0 + c];
            #pragma unroll
            for (int r = 0; r < 4; ++r)
                #pragma unroll
                for (int c = 0; c < 8; ++c) acc2[r][c] += a[r] * ww[c];
        }
    }
    {
        float bias[8];
        #pragma unroll
        for (int c = 0; c < 8; ++c) bias[c] = bn2[o0 + c];
        #pragma unroll
        for (int r = 0; r < 4; ++r) {
            int n = n0b + ec + 16 * r;
            if (n < NN) {
                #pragma unroll
                for (int c = 0; c < 8; ++c)
                    out[(size_t)n * HID + o0 + c] =
                        xh[(size_t)n * HID + o0 + c] + silu_f(acc2[r][c] + bias[c]);
            }
        }
    }
}

extern "C" void kernel_launch(void* const* d_in, const int* in_sizes, int n_in,
                              void* d_out, int out_size, void* d_ws, size_t ws_size,
                              hipStream_t stream) {
    (void)in_sizes; (void)n_in; (void)out_size; (void)ws_size;
    const float* x      = (const float*)d_in[0];
    const float* weight = (const float*)d_in[1];
    const float* ln_g   = (const float*)d_in[2];
    const float* ln_b   = (const float*)d_in[3];
    const float* We1    = (const float*)d_in[4];
    const float* be1    = (const float*)d_in[5];
    const float* We2    = (const float*)d_in[6];
    const float* be2    = (const float*)d_in[7];
    const float* Wa     = (const float*)d_in[8];
    const float* ba     = (const float*)d_in[9];
    const float* Wn1    = (const float*)d_in[10];
    const float* bn1    = (const float*)d_in[11];
    const float* Wn2    = (const float*)d_in[12];
    const float* bn2    = (const float*)d_in[13];
    const float* Wo     = (const float*)d_in[14];
    const float* bo     = (const float*)d_in[15];
    const int*   eidx   = (const int*)d_in[16];
    const int* ii = eidx;
    const int* jj = eidx + NE;

    float*  xh   = (float*)d_ws;                 // 1,280,000 f
    float*  agg  = xh + (size_t)NN * HID;        // 1,280,000 f
    float*  cnt  = agg + (size_t)NN * HID;       // 10,000 f
    __half* xh_h = (__half*)(cnt + NN);          // 1,280,000 h
    __half* We1p = xh_h + (size_t)NN * HID;      // 86,016 h (21 tiles)
    __half* We2p = We1p + 86016;                 // 16,384 h (4 tiles)
    __half* Wop  = We2p + 16384;                 // 53,248 h (3x4 tiles + 4 small)

    float* xh_out = (float*)d_out;
    float* edgeh  = xh_out + (size_t)NN * HID;

    hipMemsetAsync(agg, 0, ((size_t)NN * HID + NN) * sizeof(float), stream);
    pack_kernel<<<76, 256, 0, stream>>>(We1, We2, Wo, We1p, We2p, Wop);
    ln_kernel<<<(NN + 3) / 4, 256, 0, stream>>>(x, ln_g, ln_b, xh, xh_h);
    edge_kernel<<<NE / EB, 256, 0, stream>>>(xh_h, weight, We1p, be1, We2p, be2,
                                             Wa, ba, Wop, bo, ii, jj,
                                             agg, cnt, edgeh);
    node_kernel<<<(NN + NT - 1) / NT, 256, 0, stream>>>(xh, agg, cnt,
                                                        Wn1, bn1, Wn2, bn2, xh_out);
}

// Round 3
// 957.439 us; speedup vs baseline: 1.8295x; 1.8295x over previous
//
#include <hip/hip_runtime.h>
#include <hip/hip_fp16.h>
#include <math.h>

#define HID  128
#define EDIM 416
#define CATD 672      // 2*HID + EDIM
#define NN   10000
#define NE   160000
#define EB   128      // edges per block (edge kernel)
#define NT   64       // nodes per block (node kernel)
#define KT   32       // K tile (node kernel)

typedef _Float16 f16x8 __attribute__((ext_vector_type(8)));
typedef float    f32x4 __attribute__((ext_vector_type(4)));

__device__ __forceinline__ float silu_f(float x) {
    return x / (1.0f + __expf(-x));
}

__device__ __forceinline__ unsigned int cvt2(float a, float b) {
    __half2 h = __floats2half2_rn(a, b);
    union { __half2 h2; unsigned int u; } c; c.h2 = h; return c.u;
}

// pack 8 fp32 (as raw bits in 2 uint4) -> 8 f16 in one uint4
__device__ __forceinline__ uint4 pack8(uint4 a, uint4 b) {
    uint4 p;
    p.x = cvt2(__uint_as_float(a.x), __uint_as_float(a.y));
    p.y = cvt2(__uint_as_float(a.z), __uint_as_float(a.w));
    p.z = cvt2(__uint_as_float(b.x), __uint_as_float(b.y));
    p.w = cvt2(__uint_as_float(b.z), __uint_as_float(b.w));
    return p;
}

// 16-B-granule XOR swizzle helpers.
__device__ __forceinline__ f16x8 frag32(const __half* base, int row, int ks) {
    return *reinterpret_cast<const f16x8*>(base + row * 32 + ((ks ^ ((row >> 1) & 3)) << 3));
}
__device__ __forceinline__ int swz128(int row, int g) { return (g & 8) | ((g ^ row) & 7); }
__device__ __forceinline__ f16x8 frag128(const __half* base, int row, int g) {
    return *reinterpret_cast<const f16x8*>(base + row * 128 + (swz128(row, g) << 3));
}

// ---------------- CSR build: histogram -> scan -> scatter ----------------
__global__ __launch_bounds__(256) void hist_kernel(const int* __restrict__ ii,
                                                   int* __restrict__ hist) {
    int e = blockIdx.x * 256 + threadIdx.x;
    if (e < NE) atomicAdd(&hist[ii[e]], 1);
}

// single block of 256 threads; each thread scans 40 consecutive nodes
__global__ __launch_bounds__(256) void scan_kernel(const int* __restrict__ hist,
                                                   int* __restrict__ rowptr,
                                                   int* __restrict__ head) {
    __shared__ int wavesum[4];
    int t = threadIdx.x;
    int base = t * 40;
    int local[40];
    int s = 0;
    #pragma unroll
    for (int u = 0; u < 40; ++u) {
        int n = base + u;
        int v = (n < NN) ? hist[n] : 0;
        local[u] = s;
        s += v;
    }
    int lane = t & 63, w = t >> 6;
    int incl = s;
    #pragma unroll
    for (int off = 1; off < 64; off <<= 1) {
        int v = __shfl_up(incl, off);
        if (lane >= off) incl += v;
    }
    if (lane == 63) wavesum[w] = incl;
    int exclLane = incl - s;
    __syncthreads();
    int waveOff = 0;
    for (int i = 0; i < w; ++i) waveOff += wavesum[i];
    int off0 = waveOff + exclLane;
    #pragma unroll
    for (int u = 0; u < 40; ++u) {
        int n = base + u;
        if (n < NN) { rowptr[n] = off0 + local[u]; head[n] = off0 + local[u]; }
    }
    if (t == 255) rowptr[NN] = off0 + s;   // == NE
}

__global__ __launch_bounds__(256) void scatter_kernel(const int* __restrict__ ii,
                                                      int* __restrict__ head,
                                                      int* __restrict__ order) {
    int e = blockIdx.x * 256 + threadIdx.x;
    if (e < NE) {
        int p = atomicAdd(&head[ii[e]], 1);
        order[p] = e;
    }
}

// ---------------- agg: one wave per node, mean over CSR edge list ----------------
__global__ __launch_bounds__(256) void agg_kernel(const __half* __restrict__ m_out,
                                                  const int* __restrict__ rowptr,
                                                  const int* __restrict__ order,
                                                  float* __restrict__ agg) {
    int node = blockIdx.x * 4 + (threadIdx.x >> 6);
    int lane = threadIdx.x & 63;
    if (node >= NN) return;
    int beg = rowptr[node], end = rowptr[node + 1];
    float a0 = 0.f, a1 = 0.f;
    int k = beg;
    for (; k + 1 < end; k += 2) {
        int e0 = order[k], e1 = order[k + 1];
        float2 f0 = __half22float2(*(const __half2*)(m_out + (size_t)e0 * HID + lane * 2));
        float2 f1 = __half22float2(*(const __half2*)(m_out + (size_t)e1 * HID + lane * 2));
        a0 += f0.x + f1.x; a1 += f0.y + f1.y;
    }
    if (k < end) {
        int e0 = order[k];
        float2 f0 = __half22float2(*(const __half2*)(m_out + (size_t)e0 * HID + lane * 2));
        a0 += f0.x; a1 += f0.y;
    }
    int deg = end - beg;
    float invd = (deg > 0) ? 1.f / (float)deg : 0.f;
    float2 r; r.x = a0 * invd; r.y = a1 * invd;
    *(float2*)(agg + (size_t)node * HID + lane * 2) = r;
}

// ---------------- LayerNorm: one wave per node; emits fp32 + fp16 ----------------
__global__ __launch_bounds__(256) void ln_kernel(const float* __restrict__ x,
                                                 const float* __restrict__ g,
                                                 const float* __restrict__ b,
                                                 float* __restrict__ xh,
                                                 __half* __restrict__ xh_h) {
    int node = blockIdx.x * 4 + (threadIdx.x >> 6);
    int lane = threadIdx.x & 63;
    if (node >= NN) return;
    const float* xr = x + (size_t)node * HID;
    float v0 = xr[lane], v1 = xr[lane + 64];
    float s = v0 + v1;
    #pragma unroll
    for (int off = 1; off < 64; off <<= 1) s += __shfl_xor(s, off);
    float mu = s * (1.0f / HID);
    float d0 = v0 - mu, d1 = v1 - mu;
    float vs = d0 * d0 + d1 * d1;
    #pragma unroll
    for (int off = 1; off < 64; off <<= 1) vs += __shfl_xor(vs, off);
    float rstd = rsqrtf(vs * (1.0f / HID) + 1e-5f);
    float r0 = d0 * rstd * g[lane]      + b[lane];
    float r1 = d1 * rstd * g[lane + 64] + b[lane + 64];
    float* o = xh + (size_t)node * HID;
    o[lane] = r0; o[lane + 64] = r1;
    __half* oh = xh_h + (size_t)node * HID;
    oh[lane]      = __float2half(r0);
    oh[lane + 64] = __float2half(r1);
}

// ---------------- Weight pack: fp32 -> fp16, B-fragment order, swizzle baked in ---
__global__ __launch_bounds__(256) void pack_kernel(
    const float* __restrict__ We1, const float* __restrict__ We2,
    const float* __restrict__ Wo,
    __half* __restrict__ We1p, __half* __restrict__ We2p, __half* __restrict__ Wop)
{
    int gid = blockIdx.x * 256 + threadIdx.x;
    if (gid < 10752) {                       // We1p: 21 tiles x 512 granules
        int kt = gid >> 9, r = gid & 511, col = r >> 2, kx = r & 3;
        __half* d = We1p + kt * 4096 + col * 32 + ((kx ^ ((col >> 1) & 3)) << 3);
        int k0 = kt * 32 + kx * 8;
        #pragma unroll
        for (int u = 0; u < 8; ++u) d[u] = __float2half(We1[(size_t)(k0 + u) * HID + col]);
    } else if (gid < 12800) {                // We2p: 4 tiles x 512
        int r2 = gid - 10752;
        int kt = r2 >> 9, r = r2 & 511, col = r >> 2, kx = r & 3;
        __half* d = We2p + kt * 4096 + col * 32 + ((kx ^ ((col >> 1) & 3)) << 3);
        int k0 = kt * 32 + kx * 8;
        #pragma unroll
        for (int u = 0; u < 8; ++u) d[u] = __float2half(We2[(size_t)(k0 + u) * HID + col]);
    } else if (gid < 18944) {                // Wop chunks 0..2: 3 x 4 tiles x 512
        int r3 = gid - 12800;
        int nc = r3 >> 11, r2 = r3 & 2047;
        int kt = r2 >> 9, r = r2 & 511, col = r >> 2, kx = r & 3;
        __half* d = Wop + nc * 16384 + kt * 4096 + col * 32 + ((kx ^ ((col >> 1) & 3)) << 3);
        int k0 = kt * 32 + kx * 8, cg = nc * 128 + col;
        #pragma unroll
        for (int u = 0; u < 8; ++u) d[u] = __float2half(Wo[(size_t)(k0 + u) * EDIM + cg]);
    } else if (gid < 19456) {                // Wop chunk 3 (cols 384..415): 4 tiles x 128
        int r3 = gid - 18944;
        int kt = r3 >> 7, r = r3 & 127, col = r >> 2, kx = r & 3;
        __half* d = Wop + 49152 + kt * 1024 + col * 32 + ((kx ^ ((col >> 1) & 3)) << 3);
        int k0 = kt * 32 + kx * 8, cg = 384 + col;
        #pragma unroll
        for (int u = 0; u < 8; ++u) d[u] = __float2half(Wo[(size_t)(k0 + u) * EDIM + cg]);
    }
}

// ---------------- Edge kernel: 128 edges/block, 4 waves (2x2), f16 MFMA ----------
// Double-buffered K-loops. m_out != nullptr: stream m_ij to global (CSR path).
// m_out == nullptr: legacy fp32-atomic aggregation into agg/cnt.
__global__ __launch_bounds__(256, 3) void edge_kernel(
    const __half* __restrict__ xh_h,
    const float*  __restrict__ weight,
    const __half* __restrict__ We1p, const float* __restrict__ be1,
    const __half* __restrict__ We2p, const float* __restrict__ be2,
    const float*  __restrict__ Wa,   const float* __restrict__ ba,
    const __half* __restrict__ Wop,  const float* __restrict__ bo,
    const int* __restrict__ ii, const int* __restrict__ jj,
    float* __restrict__ agg, float* __restrict__ cnt,
    __half* __restrict__ m_out,
    float* __restrict__ edgeh)
{
    __shared__ __half smem[24576];        // 48 KB: A0(4096h) B0(4096h) ml(16384h)
    __shared__ float  attv[EB];
    __shared__ float  Was[HID];
    __shared__ int    iis_s[EB], jjs_s[EB];

    __half* const A0 = smem;
    __half* const B0 = smem + 4096;
    __half* const ml = smem + 8192;
    __half* const A1 = ml;                // alias: GEMM1 only (ml not yet live)
    __half* const B1 = ml + 4096;         // alias: GEMM1 only

    const int t    = threadIdx.x;
    const int e0   = blockIdx.x * EB;
    const int lane = t & 63;
    const int w    = t >> 6;
    const int wr   = w >> 1, wc = w & 1;
    const int li   = lane & 15, ks = lane >> 4;
    const int rbw  = wr * 64, cbw = wc * 64;
    const int e_lo = t >> 2, kx = t & 3;
    const int sw_lo = ((kx ^ ((e_lo >> 1) & 3)) << 3);

    if (t < EB) { iis_s[t] = ii[e0 + t]; jjs_s[t] = jj[e0 + t]; }
    if (t < HID) Was[t] = Wa[t];
    __syncthreads();

    // ---- GEMM1 prologue: stage tile 0 ----
    {
        int n0 = iis_s[e_lo], n1 = iis_s[e_lo + 64];
        uint4 a0v = *(const uint4*)(xh_h + (size_t)n0 * HID + kx * 8);
        uint4 a1v = *(const uint4*)(xh_h + (size_t)n1 * HID + kx * 8);
        uint4 b0v = *(const uint4*)(We1p + t * 8);
        uint4 b1v = *(const uint4*)(We1p + 2048 + t * 8);
        *(uint4*)(A0 + e_lo * 32 + sw_lo) = a0v;
        *(uint4*)(A0 + (e_lo + 64) * 32 + sw_lo) = a1v;
        *(uint4*)(B0 + t * 8) = b0v;
        *(uint4*)(B0 + 2048 + t * 8) = b1v;
    }
    __syncthreads();

    // ================= GEMM1: cat(672) @ We1 -> 128 (double-buffered) =========
    f32x4 acc[4][4];
    #pragma unroll
    for (int fr = 0; fr < 4; ++fr)
        #pragma unroll
        for (int fc = 0; fc < 4; ++fc) {
            acc[fr][fc][0] = 0.f; acc[fr][fc][1] = 0.f;
            acc[fr][fc][2] = 0.f; acc[fr][fc][3] = 0.f;
        }

    #pragma unroll 1
    for (int kt = 0; kt < 21; ++kt) {
        const int ktn = kt + 1;
        uint4 pa0, pa1, pa2, pa3, pb0, pb1;
        if (ktn < 21) {
            const __half* bsrc = We1p + ktn * 4096;
            pb0 = *(const uint4*)(bsrc + t * 8);
            pb1 = *(const uint4*)(bsrc + 2048 + t * 8);
            if (ktn < 8) {
                int n0 = (ktn < 4) ? iis_s[e_lo] : jjs_s[e_lo];
                int n1 = (ktn < 4) ? iis_s[e_lo + 64] : jjs_s[e_lo + 64];
                pa0 = *(const uint4*)(xh_h + (size_t)n0 * HID + (ktn & 3) * 32 + kx * 8);
                pa1 = *(const uint4*)(xh_h + (size_t)n1 * HID + (ktn & 3) * 32 + kx * 8);
            } else {
                const float* s0p = weight + (size_t)(e0 + e_lo) * EDIM + (ktn - 8) * 32 + kx * 8;
                const float* s1p = weight + (size_t)(e0 + e_lo + 64) * EDIM + (ktn - 8) * 32 + kx * 8;
                pa0 = ((const uint4*)s0p)[0]; pa1 = ((const uint4*)s0p)[1];
                pa2 = ((const uint4*)s1p)[0]; pa3 = ((const uint4*)s1p)[1];
            }
        }
        const __half* Ac = (kt & 1) ? A1 : A0;
        const __half* Bc = (kt & 1) ? B1 : B0;
        f16x8 av[4], bv[4];
        #pragma unroll
        for (int fr = 0; fr < 4; ++fr) av[fr] = frag32(Ac, rbw + fr * 16 + li, ks);
        #pragma unroll
        for (int fc = 0; fc < 4; ++fc) bv[fc] = frag32(Bc, cbw + fc * 16 + li, ks);
        #pragma unroll
        for (int fr = 0; fr < 4; ++fr)
            #pragma unroll
            for (int fc = 0; fc < 4; ++fc)
                acc[fr][fc] = __builtin_amdgcn_mfma_f32_16x16x32_f16(av[fr], bv[fc], acc[fr][fc], 0, 0, 0);
        if (ktn < 21) {
            __half* An = (ktn & 1) ? A1 : A0;
            __half* Bn = (ktn & 1) ? B1 : B0;
            *(uint4*)(Bn + t * 8) = pb0;
            *(uint4*)(Bn + 2048 + t * 8) = pb1;
            if (ktn < 8) {
                *(uint4*)(An + e_lo * 32 + sw_lo) = pa0;
                *(uint4*)(An + (e_lo + 64) * 32 + sw_lo) = pa1;
            } else {
                *(uint4*)(An + e_lo * 32 + sw_lo) = pack8(pa0, pa1);
                *(uint4*)(An + (e_lo + 64) * 32 + sw_lo) = pack8(pa2, pa3);
            }
        }
        __syncthreads();
    }

    // m1 = silu(acc + be1) -> ml
    #pragma unroll
    for (int fc = 0; fc < 4; ++fc) {
        int c = cbw + fc * 16 + li;
        float bias = be1[c];
        int gc = c >> 3;
        #pragma unroll
        for (int fr = 0; fr < 4; ++fr)
            #pragma unroll
            for (int bb = 0; bb < 4; ++bb) {
                int e = rbw + fr * 16 + 4 * ks + bb;
                ml[e * 128 + (swz128(e, gc) << 3) + (c & 7)] =
                    __float2half(silu_f(acc[fr][fc][bb] + bias));
            }
    }
    {
        uint4 b0v = *(const uint4*)(We2p + t * 8);
        uint4 b1v = *(const uint4*)(We2p + 2048 + t * 8);
        *(uint4*)(B0 + t * 8) = b0v;
        *(uint4*)(B0 + 2048 + t * 8) = b1v;
    }
    __syncthreads();

    // ================= GEMM2: m1(128) @ We2 -> 128 =================
    f32x4 acc2[4][4];
    #pragma unroll
    for (int fr = 0; fr < 4; ++fr)
        #pragma unroll
        for (int fc = 0; fc < 4; ++fc) {
            acc2[fr][fc][0] = 0.f; acc2[fr][fc][1] = 0.f;
            acc2[fr][fc][2] = 0.f; acc2[fr][fc][3] = 0.f;
        }
    #pragma unroll 1
    for (int kt = 0; kt < 4; ++kt) {
        uint4 pb0, pb1;
        if (kt < 3) {
            const __half* bsrc = We2p + (kt + 1) * 4096;
            pb0 = *(const uint4*)(bsrc + t * 8);
            pb1 = *(const uint4*)(bsrc + 2048 + t * 8);
        }
        const __half* Bc = (kt & 1) ? A0 : B0;
        f16x8 av[4], bv[4];
        #pragma unroll
        for (int fr = 0; fr < 4; ++fr) av[fr] = frag128(ml, rbw + fr * 16 + li, kt * 4 + ks);
        #pragma unroll
        for (int fc = 0; fc < 4; ++fc) bv[fc] = frag32(Bc, cbw + fc * 16 + li, ks);
        #pragma unroll
        for (int fr = 0; fr < 4; ++fr)
            #pragma unroll
            for (int fc = 0; fc < 4; ++fc)
                acc2[fr][fc] = __builtin_amdgcn_mfma_f32_16x16x32_f16(av[fr], bv[fc], acc2[fr][fc], 0, 0, 0);
        if (kt < 3) {
            __half* Bn = ((kt + 1) & 1) ? A0 : B0;
            *(uint4*)(Bn + t * 8) = pb0;
            *(uint4*)(Bn + 2048 + t * 8) = pb1;
        }
        __syncthreads();
    }
    #pragma unroll
    for (int fc = 0; fc < 4; ++fc) {
        int c = cbw + fc * 16 + li;
        float bias = be2[c];
        int gc = c >> 3;
        #pragma unroll
        for (int fr = 0; fr < 4; ++fr)
            #pragma unroll
            for (int bb = 0; bb < 4; ++bb) {
                int e = rbw + fr * 16 + 4 * ks + bb;
                ml[e * 128 + (swz128(e, gc) << 3) + (c & 7)] =
                    __float2half(silu_f(acc2[fr][fc][bb] + bias));
            }
    }
    __syncthreads();

    // ================= attention: att = silu(m . Wa + ba) =================
    {
        int e = t >> 1, h = t & 1;
        float sum = 0.f;
        #pragma unroll
        for (int g8 = 0; g8 < 8; ++g8) {
            int g = h * 8 + g8;
            uint4 v = *(const uint4*)(ml + e * 128 + (swz128(e, g) << 3));
            const __half* hp = (const __half*)&v;
            #pragma unroll
            for (int u = 0; u < 8; ++u) sum += __half2float(hp[u]) * Was[g * 8 + u];
        }
        sum += __shfl_xor(sum, 1);
        if (h == 0) attv[e] = silu_f(sum + ba[0]);
    }
    __syncthreads();

    // ====== m_ij = m * att (in place); CSR path streams m_ij to global ======
    {
        int e = t >> 1, h = t & 1;
        __half2 a2 = __float2half2_rn(attv[e]);
        __half* mrow = m_out + (size_t)(e0 + e) * HID;   // unused if m_out==nullptr
        #pragma unroll
        for (int g8 = 0; g8 < 8; ++g8) {
            int g = h * 8 + g8;
            uint4* p4 = (uint4*)(ml + e * 128 + (swz128(e, g) << 3));
            uint4 v = *p4;
            __half2* h2 = (__half2*)&v;
            #pragma unroll
            for (int i = 0; i < 4; ++i) h2[i] = __hmul2(h2[i], a2);
            *p4 = v;
            if (m_out) *(uint4*)(mrow + g * 8) = v;      // coalesced-ish 16B stores
        }
    }
    {   // stage Wop tile L=0 into B0
        uint4 b0v = *(const uint4*)(Wop + t * 8);
        uint4 b1v = *(const uint4*)(Wop + 2048 + t * 8);
        *(uint4*)(B0 + t * 8) = b0v;
        *(uint4*)(B0 + 2048 + t * 8) = b1v;
    }
    __syncthreads();

    // ===== GEMM3: m_ij(128) @ Wo -> 416 (linear 16-tile loop) =====
    f32x4 acc3[4][4];
    #pragma unroll 1
    for (int L = 0; L < 16; ++L) {
        const int nc = L >> 2, kt = L & 3;
        if (kt == 0) {
            #pragma unroll
            for (int fr = 0; fr < 4; ++fr)
                #pragma unroll
                for (int fc = 0; fc < 4; ++fc) {
                    acc3[fr][fc][0] = 0.f; acc3[fr][fc][1] = 0.f;
                    acc3[fr][fc][2] = 0.f; acc3[fr][fc][3] = 0.f;
                }
        }
        uint4 pb0, pb1;
        const int Ln = L + 1;
        if (Ln < 16) {
            const int ncn = Ln >> 2, ktn = Ln & 3;
            if (ncn < 3) {
                const __half* bsrc = Wop + ncn * 16384 + ktn * 4096;
                pb0 = *(const uint4*)(bsrc + t * 8);
                pb1 = *(const uint4*)(bsrc + 2048 + t * 8);
            } else if (t < 128) {
                pb0 = *(const uint4*)(Wop + 49152 + ktn * 1024 + t * 8);
            }
        }
        const __half* Bc = (L & 1) ? A0 : B0;
        f16x8 av[4];
        #pragma unroll
        for (int fr = 0; fr < 4; ++fr) av[fr] = frag128(ml, rbw + fr * 16 + li, kt * 4 + ks);
        if (nc < 3) {
            f16x8 bv[4];
            #pragma unroll
            for (int fc = 0; fc < 4; ++fc) bv[fc] = frag32(Bc, cbw + fc * 16 + li, ks);
            #pragma unroll
            for (int fr = 0; fr < 4; ++fr)
                #pragma unroll
                for (int fc = 0; fc < 4; ++fc)
                    acc3[fr][fc] = __builtin_amdgcn_mfma_f32_16x16x32_f16(av[fr], bv[fc], acc3[fr][fc], 0, 0, 0);
        } else {
            f16x8 bv = frag32(Bc, wc * 16 + li, ks);
            #pragma unroll
            for (int fr = 0; fr < 4; ++fr)
                acc3[fr][0] = __builtin_amdgcn_mfma_f32_16x16x32_f16(av[fr], bv, acc3[fr][0], 0, 0, 0);
        }
        if (Ln < 16) {
            __half* Bn = (Ln & 1) ? A0 : B0;
            if ((Ln >> 2) < 3) {
                *(uint4*)(Bn + t * 8) = pb0;
                *(uint4*)(Bn + 2048 + t * 8) = pb1;
            } else if (t < 128) {
                *(uint4*)(Bn + t * 8) = pb0;
            }
        }
        __syncthreads();
        if (kt == 3) {
            if (nc < 3) {
                #pragma unroll
                for (int fc = 0; fc < 4; ++fc) {
                    int cg = nc * 128 + cbw + fc * 16 + li;
                    float bias = bo[cg];
                    #pragma unroll
                    for (int fr = 0; fr < 4; ++fr)
                        #pragma unroll
                        for (int bb = 0; bb < 4; ++bb) {
                            int e = rbw + fr * 16 + 4 * ks + bb;
                            size_t idx = (size_t)(e0 + e) * EDIM + cg;
                            edgeh[idx] = weight[idx] + silu_f(acc3[fr][fc][bb] + bias);
                        }
                }
            } else {
                int cg = 384 + wc * 16 + li;
                float bias = bo[cg];
                #pragma unroll
                for (int fr = 0; fr < 4; ++fr)
                    #pragma unroll
                    for (int bb = 0; bb < 4; ++bb) {
                        int e = rbw + fr * 16 + 4 * ks + bb;
                        size_t idx = (size_t)(e0 + e) * EDIM + cg;
                        edgeh[idx] = weight[idx] + silu_f(acc3[fr][0][bb] + bias);
                    }
            }
        }
    }

    // ====== legacy fallback: fp32 atomic aggregation (only if m_out==nullptr) ======
    if (!m_out) {
        int e = t >> 1, h = t & 1;
        int node = iis_s[e];
        float* aggrow = agg + (size_t)node * HID;
        #pragma unroll
        for (int g8 = 0; g8 < 8; ++g8) {
            int g = h * 8 + g8;
            uint4 v = *(const uint4*)(ml + e * 128 + (swz128(e, g) << 3));
            const __half* hp = (const __half*)&v;
            #pragma unroll
            for (int u = 0; u < 8; ++u)
                atomicAdd(aggrow + g * 8 + u, __half2float(hp[u]));
        }
        if (h == 0) atomicAdd(&cnt[node], 1.0f);
    }
}

// ---------------- Node kernel: 64 nodes x 128 outs per block (fp32) ----------
// cnt == nullptr: agg is already the mean (CSR path).
__global__ __launch_bounds__(256) void node_kernel(
    const float* __restrict__ xh,
    const float* __restrict__ agg, const float* __restrict__ cnt,
    const float* __restrict__ Wn1, const float* __restrict__ bn1,
    const float* __restrict__ Wn2, const float* __restrict__ bn2,
    float* __restrict__ out)
{
    __shared__ float catile[NT][KT + 1];
    __shared__ float wls[KT][HID];
    __shared__ float mls[NT][HID + 4];
    __shared__ float inv[NT];

    int t   = threadIdx.x;
    int n0b = blockIdx.x * NT;

    if (t < NT) {
        float iv = 1.f;
        if (cnt) {
            int n = n0b + t;
            float c = (n < NN) ? cnt[n] : 1.f;
            iv = (c == 0.f) ? 1.f : 1.f / c;
        }
        inv[t] = iv;
    }

    int ec = t & 15, og = t >> 4, o0 = og * 8;

    float acc[4][8];
    #pragma unroll
    for (int r = 0; r < 4; ++r)
        #pragma unroll
        for (int c = 0; c < 8; ++c) acc[r][c] = 0.f;

    for (int kt = 0; kt < (2 * HID) / KT; ++kt) {
        int k0 = kt * KT;
        __syncthreads();
        #pragma unroll
        for (int j = 0; j < 8; ++j) {
            int idx = t + j * 256;
            int e = idx >> 5, k = idx & 31;
            int kk = k0 + k;
            int n = n0b + e;
            float v = 0.f;
            if (n < NN) {
                if (kk < HID) v = xh[(size_t)n * HID + kk];
                else          v = agg[(size_t)n * HID + (kk - HID)] * inv[e];
            }
            catile[e][k] = v;
        }
        #pragma unroll
        for (int j = 0; j < 16; ++j) {
            int idx = t + j * 256;
            int k = idx >> 7, o = idx & 127;
            wls[k][o] = Wn1[(size_t)(k0 + k) * HID + o];
        }
        __syncthreads();
        #pragma unroll
        for (int k = 0; k < KT; ++k) {
            float a[4], ww[8];
            #pragma unroll
            for (int r = 0; r < 4; ++r) a[r] = catile[ec + 16 * r][k];
            #pragma unroll
            for (int c = 0; c < 8; ++c) ww[c] = wls[k][o0 + c];
            #pragma unroll
            for (int r = 0; r < 4; ++r)
                #pragma unroll
                for (int c = 0; c < 8; ++c) acc[r][c] += a[r] * ww[c];
        }
    }
    {
        float bias[8];
        #pragma unroll
        for (int c = 0; c < 8; ++c) bias[c] = bn1[o0 + c];
        #pragma unroll
        for (int r = 0; r < 4; ++r)
            #pragma unroll
            for (int c = 0; c < 8; ++c)
                mls[ec + 16 * r][o0 + c] = silu_f(acc[r][c] + bias[c]);
    }

    float acc2[4][8];
    #pragma unroll
    for (int r = 0; r < 4; ++r)
        #pragma unroll
        for (int c = 0; c < 8; ++c) acc2[r][c] = 0.f;

    for (int kt = 0; kt < HID / KT; ++kt) {
        __syncthreads();
        #pragma unroll
        for (int j = 0; j < 16; ++j) {
            int idx = t + j * 256;
            int k = idx >> 7, o = idx & 127;
            wls[k][o] = Wn2[(size_t)(kt * KT + k) * HID + o];
        }
        __syncthreads();
        #pragma unroll
        for (int k = 0; k < KT; ++k) {
            float a[4], ww[8];
            #pragma unroll
            for (int r = 0; r < 4; ++r) a[r] = mls[ec + 16 * r][kt * KT + k];
            #pragma unroll
            for (int c = 0; c < 8; ++c) ww[c] = wls[k][o0 + c];
            #pragma unroll
            for (int r = 0; r < 4; ++r)
                #pragma unroll
                for (int c = 0; c < 8; ++c) acc2[r][c] += a[r] * ww[c];
        }
    }
    {
        float bias[8];
        #pragma unroll
        for (int c = 0; c < 8; ++c) bias[c] = bn2[o0 + c];
        #pragma unroll
        for (int r = 0; r < 4; ++r) {
            int n = n0b + ec + 16 * r;
            if (n < NN) {
                #pragma unroll
                for (int c = 0; c < 8; ++c)
                    out[(size_t)n * HID + o0 + c] =
                        xh[(size_t)n * HID + o0 + c] + silu_f(acc2[r][c] + bias[c]);
            }
        }
    }
}

extern "C" void kernel_launch(void* const* d_in, const int* in_sizes, int n_in,
                              void* d_out, int out_size, void* d_ws, size_t ws_size,
                              hipStream_t stream) {
    (void)in_sizes; (void)n_in; (void)out_size;
    const float* x      = (const float*)d_in[0];
    const float* weight = (const float*)d_in[1];
    const float* ln_g   = (const float*)d_in[2];
    const float* ln_b   = (const float*)d_in[3];
    const float* We1    = (const float*)d_in[4];
    const float* be1    = (const float*)d_in[5];
    const float* We2    = (const float*)d_in[6];
    const float* be2    = (const float*)d_in[7];
    const float* Wa     = (const float*)d_in[8];
    const float* ba     = (const float*)d_in[9];
    const float* Wn1    = (const float*)d_in[10];
    const float* bn1    = (const float*)d_in[11];
    const float* Wn2    = (const float*)d_in[12];
    const float* bn2    = (const float*)d_in[13];
    const float* Wo     = (const float*)d_in[14];
    const float* bo     = (const float*)d_in[15];
    const int*   eidx   = (const int*)d_in[16];
    const int* ii = eidx;
    const int* jj = eidx + NE;

    char* p = (char*)d_ws;
    auto alloc = [&](size_t bytes) { char* r = p; p += (bytes + 15) & ~(size_t)15; return r; };
    float*  xh     = (float*) alloc((size_t)NN * HID * 4);
    float*  agg    = (float*) alloc((size_t)NN * HID * 4);
    float*  cnt    = (float*) alloc((size_t)NN * 4);
    __half* xh_h   = (__half*)alloc((size_t)NN * HID * 2);
    __half* We1p   = (__half*)alloc((size_t)86016 * 2);
    __half* We2p   = (__half*)alloc((size_t)16384 * 2);
    __half* Wop    = (__half*)alloc((size_t)53248 * 2);
    int*    rowptr = (int*)   alloc((size_t)(NN + 1) * 4);
    int*    head   = (int*)   alloc((size_t)NN * 4);
    int*    order  = (int*)   alloc((size_t)NE * 4);
    __half* m_out  = (__half*)alloc((size_t)NE * HID * 2);
    size_t need = (size_t)(p - (char*)d_ws);
    bool use_csr = (ws_size >= need);

    float* xh_out = (float*)d_out;
    float* edgeh  = xh_out + (size_t)NN * HID;

    pack_kernel<<<76, 256, 0, stream>>>(We1, We2, Wo, We1p, We2p, Wop);
    ln_kernel<<<(NN + 3) / 4, 256, 0, stream>>>(x, ln_g, ln_b, xh, xh_h);

    if (use_csr) {
        // hist reuses `head` buffer first (memset), then scan converts to heads
        hipMemsetAsync(head, 0, (size_t)NN * 4, stream);
        hist_kernel<<<(NE + 255) / 256, 256, 0, stream>>>(ii, head);
        // scan: reads head (=hist), writes rowptr and resets head to row starts
        scan_kernel<<<1, 256, 0, stream>>>(head, rowptr, head);
        scatter_kernel<<<(NE + 255) / 256, 256, 0, stream>>>(ii, head, order);
        edge_kernel<<<NE / EB, 256, 0, stream>>>(xh_h, weight, We1p, be1, We2p, be2,
                                                 Wa, ba, Wop, bo, ii, jj,
                                                 nullptr, nullptr, m_out, edgeh);
        agg_kernel<<<(NN + 3) / 4, 256, 0, stream>>>(m_out, rowptr, order, agg);
        node_kernel<<<(NN + NT - 1) / NT, 256, 0, stream>>>(xh, agg, nullptr,
                                                            Wn1, bn1, Wn2, bn2, xh_out);
    } else {
        hipMemsetAsync(agg, 0, ((size_t)NN * HID + NN) * sizeof(float), stream);
        edge_kernel<<<NE / EB, 256, 0, stream>>>(xh_h, weight, We1p, be1, We2p, be2,
                                                 Wa, ba, Wop, bo, ii, jj,
                                                 agg, cnt, nullptr, edgeh);
        node_kernel<<<(NN + NT - 1) / NT, 256, 0, stream>>>(xh, agg, cnt,
                                                            Wn1, bn1, Wn2, bn2, xh_out);
    }
}